// Round 3
// baseline (143.330 us; speedup 1.0000x reference)
//
#include <hip/hip_runtime.h>
#include <math.h>

// Problem constants (match reference)
#define NSEQ 64
#define TLEN 32768
#define G16_PER_SEQ 2048               // TLEN/16
#define NG16 (NSEQ * G16_PER_SEQ)      // 131072 level-16 groups
#define NTHREADS (NG16 * 4)            // 524288 threads, 4 gyro steps each
#define BLOCK 256
#define NBLOCKS (NTHREADS / BLOCK)     // 2048
#define N0 5
#define DT 0.01f
#define HUBER_INV 200.0f               // 1/0.005

// W*HUBER^2 = 25.  mean denominators: 64*2043*3 and 64*1019*3; level-32 has extra 1/2.
__device__ __constant__ float C16 = 25.0f / (64.0f * 2043.0f * 3.0f);
__device__ __constant__ float C32 = 12.5f / (64.0f * 1019.0f * 3.0f);

__device__ __forceinline__ void mat_mul3(const float* A, const float* B, float* C) {
#pragma unroll
    for (int i = 0; i < 3; ++i) {
#pragma unroll
        for (int j = 0; j < 3; ++j) {
            C[3 * i + j] = A[3 * i + 0] * B[0 + j]
                         + A[3 * i + 1] * B[3 + j]
                         + A[3 * i + 2] * B[6 + j];
        }
    }
}

// Build R from s=sin(a)/a, c=(1-cos a)/a^2 and phi=(x,y,z)
__device__ __forceinline__ void rodrigues(float x, float y, float z, float s, float c, float* R) {
    float cxx = c * x * x, cyy = c * y * y, czz = c * z * z;
    float cxy = c * x * y, cxz = c * x * z, cyz = c * y * z;
    float sx = s * x, sy = s * y, sz = s * z;
    R[0] = 1.0f - cyy - czz; R[1] = cxy - sz;          R[2] = cxz + sy;
    R[3] = cxy + sz;         R[4] = 1.0f - cxx - czz;  R[5] = cyz - sx;
    R[6] = cxz - sy;         R[7] = cyz + sx;          R[8] = 1.0f - cxx - cyy;
}

// Small-angle so3_exp: |phi| = DT*|N(0,1)_3| < 0.3 in practice -> 3-term series,
// abs err ~1e-8 vs exact (threshold is 2% relative on a ~6400 scalar).
__device__ __forceinline__ void so3_exp_small(float x, float y, float z, float* R) {
    float sq = x * x + y * y + z * z;
    float s = 1.0f - (sq * (1.0f / 6.0f)) * (1.0f - sq * (1.0f / 20.0f));
    float c = 0.5f - (sq * (1.0f / 24.0f)) * (1.0f - sq * (1.0f / 30.0f));
    rodrigues(x, y, z, s, c, R);
}

// Full so3_exp matching the reference branches (angles up to ~6 for xs)
__device__ __forceinline__ void so3_exp_dev(float x, float y, float z, float* R) {
    float sq = x * x + y * y + z * z;
    float angle = sqrtf(fmaxf(sq, 1e-16f));
    bool small = sq < 1e-12f;
    float a = small ? 1.0f : angle;
    float sn, cs;
    __sincosf(a, &sn, &cs);
    float s = small ? (1.0f - sq * (1.0f / 6.0f)) : (sn / a);
    float c = small ? (0.5f - sq * (1.0f / 24.0f)) : ((1.0f - cs) / (a * a));
    rodrigues(x, y, z, s, c, R);
}

// huber-sum over 3 components of log(Om^T * Xr) / HUBER
__device__ __forceinline__ float huber3_bmtm_log(const float* Om, const float* Xr) {
    float M[9];
#pragma unroll
    for (int j = 0; j < 3; ++j) {
#pragma unroll
        for (int k = 0; k < 3; ++k) {
            M[3 * j + k] = Om[0 + j] * Xr[0 + k]
                         + Om[3 + j] * Xr[3 + k]
                         + Om[6 + j] * Xr[6 + k];
        }
    }
    float tr = M[0] + M[4] + M[8];
    float cosv = 0.5f * (tr - 1.0f);
    cosv = fminf(fmaxf(cosv, -1.0f + 1e-7f), 1.0f - 1e-7f);
    float angle = acosf(cosv);
    float sn = sqrtf(fmaxf(1.0f - cosv * cosv, 0.0f));   // sin(acos(x)), angle in (0,pi)
    float sfac = angle / (2.0f * sn);
    float v0 = sfac * (M[7] - M[5]);
    float v1 = sfac * (M[2] - M[6]);
    float v2 = sfac * (M[3] - M[1]);
    float acc = 0.0f;
#pragma unroll
    for (int t = 0; t < 3; ++t) {
        float zz = (t == 0 ? v0 : (t == 1 ? v1 : v2)) * HUBER_INV;
        float az = fabsf(zz);
        acc += (az < 1.0f) ? 0.5f * zz * zz : az - 0.5f;
    }
    return acc;
}

// Ordered non-commutative butterfly combine across lanes (xor mask).
// upper==true -> partner's matrix multiplies on the left.
__device__ __forceinline__ void ordered_combine(float* A, int mask, bool upper) {
    float L[9], R[9];
#pragma unroll
    for (int t = 0; t < 9; ++t) {
        float b = __shfl_xor(A[t], mask);
        L[t] = upper ? b : A[t];
        R[t] = upper ? A[t] : b;
    }
    float C[9];
    mat_mul3(L, R, C);
#pragma unroll
    for (int t = 0; t < 9; ++t) A[t] = C[t];
}

__global__ __launch_bounds__(256, 4) void gyro_loss_kernel(const float* __restrict__ xs,
                                                           const float* __restrict__ hat_xs,
                                                           float* __restrict__ acc,
                                                           unsigned int* __restrict__ ctr,
                                                           float* __restrict__ out) {
    const int tid = threadIdx.x;
    const int gt = blockIdx.x * BLOCK + tid;          // global thread id

    // ---- direct load: this thread's 4 steps = 48 contiguous bytes (3 x float4) ----
    const float4* hp = reinterpret_cast<const float4*>(hat_xs) + (size_t)gt * 3;
    float4 h0 = hp[0], h1 = hp[1], h2 = hp[2];

    // ---- product of this thread's 4 per-step rotations (tree, depth 2) ----
    float Ra[9], Rb[9], P[9], Q[9], Om[9];
    so3_exp_small(DT * h0.x, DT * h0.y, DT * h0.z, Ra);
    so3_exp_small(DT * h0.w, DT * h1.x, DT * h1.y, Rb);
    mat_mul3(Ra, Rb, P);
    so3_exp_small(DT * h1.z, DT * h1.w, DT * h2.x, Ra);
    so3_exp_small(DT * h2.y, DT * h2.z, DT * h2.w, Rb);
    mat_mul3(Ra, Rb, Q);
    mat_mul3(P, Q, Om);

    // ---- butterfly to the 16-step product (quad lanes; xor1/xor2 lower to DPP) ----
    ordered_combine(Om, 1, (tid & 1) != 0);
    ordered_combine(Om, 2, (tid & 2) != 0);
    const int g = gt >> 2;                             // level-16 group id

    // ---- xs_r for this group (all quad lanes load the same float4 -> broadcast) ----
    float4 xv = *(reinterpret_cast<const float4*>(xs) + (size_t)g * 12);
    float Xr[9];
    so3_exp_dev(xv.x, xv.y, xv.z, Xr);

    // keep level-16 copies, then combine to level 32 in place
    float Om16[9], Xr16[9];
#pragma unroll
    for (int t = 0; t < 9; ++t) { Om16[t] = Om[t]; Xr16[t] = Xr[t]; }
    ordered_combine(Om, 4, (tid & 4) != 0);
    ordered_combine(Xr, 4, (tid & 4) != 0);

    // ---- one predicated huber/log section on disjoint lanes ----
    // lane (tid&3)==1 of each quad: level-16 term; lane (tid&7)==0: level-32 term
    bool do16 = ((tid & 3) == 1) && ((g & (G16_PER_SEQ - 1)) >= N0);
    bool do32 = ((tid & 7) == 0) && (((g >> 1) & (G16_PER_SEQ / 2 - 1)) >= N0);
    float partial = 0.0f;
    if (do16 || do32) {
        float A[9], B[9];
#pragma unroll
        for (int t = 0; t < 9; ++t) {
            A[t] = do32 ? Om[t] : Om16[t];
            B[t] = do32 ? Xr[t] : Xr16[t];
        }
        float w = do32 ? C32 : C16;
        partial = w * huber3_bmtm_log(A, B);
    }

    // ---- block reduction ----
#pragma unroll
    for (int off = 32; off > 0; off >>= 1) partial += __shfl_down(partial, off);
    __shared__ float wsum[4];
    if ((tid & 63) == 0) wsum[tid >> 6] = partial;
    __syncthreads();

    if (tid == 0) {
        float bsum = wsum[0] + wsum[1] + wsum[2] + wsum[3];
        atomicAdd(acc, bsum);                        // device-scope, L2 coherence point
        __threadfence();
        unsigned int old = atomicAdd(ctr, 1u);
        if (old == NBLOCKS - 1) {                    // last block: total is complete
            float total = atomicAdd(acc, 0.0f);      // atomic read of the final sum
            out[0] = total;
        }
    }
}

extern "C" void kernel_launch(void* const* d_in, const int* in_sizes, int n_in,
                              void* d_out, int out_size, void* d_ws, size_t ws_size,
                              hipStream_t stream) {
    const float* xs     = (const float*)d_in[0];
    // d_in[1] = dp, unused by the forward pass
    const float* hat_xs = (const float*)d_in[2];
    float* out = (float*)d_out;

    float* acc        = (float*)d_ws;                 // [0]: running sum
    unsigned int* ctr = (unsigned int*)d_ws + 1;      // [1]: arrival counter

    hipMemsetAsync(d_ws, 0, 8, stream);               // zero acc + ctr (graph-capturable)
    gyro_loss_kernel<<<NBLOCKS, BLOCK, 0, stream>>>(xs, hat_xs, acc, ctr, out);
}

// Round 4
// 137.210 us; speedup vs baseline: 1.0446x; 1.0446x over previous
//
#include <hip/hip_runtime.h>
#include <math.h>

// Problem constants (match reference)
#define NSEQ 64
#define TLEN 32768
#define G16_PER_SEQ 2048               // TLEN/16
#define NG16 (NSEQ * G16_PER_SEQ)      // 131072 level-16 groups
#define NTHREADS (NG16 * 4)            // 524288 threads, 4 gyro steps each
#define BLOCK 256
#define NBLOCKS (NTHREADS / BLOCK)     // 2048
#define N0 5
#define DT 0.01f
#define HUBER_INV 200.0f               // 1/0.005

// d_ws layout (all zeroed by one small memset):
//   [0      , 8192 )  float partials[2048]        (one per block)
//   [8192   , 16384)  uint  subctr[64], 128B-padded (stride 32 uints)
//   [16384  , 16388)  uint  master
#define WS_SUBCTR_U32 2048
#define WS_MASTER_U32 4096
#define WS_ZERO_BYTES 16512

// W*HUBER^2 = 25.  mean denominators: 64*2043*3 and 64*1019*3; level-32 extra 1/2.
__device__ __constant__ float C16 = 25.0f / (64.0f * 2043.0f * 3.0f);
__device__ __constant__ float C32 = 12.5f / (64.0f * 1019.0f * 3.0f);

__device__ __forceinline__ void mat_mul3(const float* A, const float* B, float* C) {
#pragma unroll
    for (int i = 0; i < 3; ++i) {
#pragma unroll
        for (int j = 0; j < 3; ++j) {
            C[3 * i + j] = A[3 * i + 0] * B[0 + j]
                         + A[3 * i + 1] * B[3 + j]
                         + A[3 * i + 2] * B[6 + j];
        }
    }
}

// Build R from s=sin(a)/a, c=(1-cos a)/a^2 and phi=(x,y,z)
__device__ __forceinline__ void rodrigues(float x, float y, float z, float s, float c, float* R) {
    float cxx = c * x * x, cyy = c * y * y, czz = c * z * z;
    float cxy = c * x * y, cxz = c * x * z, cyz = c * y * z;
    float sx = s * x, sy = s * y, sz = s * z;
    R[0] = 1.0f - cyy - czz; R[1] = cxy - sz;          R[2] = cxz + sy;
    R[3] = cxy + sz;         R[4] = 1.0f - cxx - czz;  R[5] = cyz - sx;
    R[6] = cxz - sy;         R[7] = cyz + sx;          R[8] = 1.0f - cxx - cyy;
}

// Small-angle so3_exp: |phi| = DT*|N(0,1)_3| < ~0.06 -> 3-term series, err ~1e-10
__device__ __forceinline__ void so3_exp_small(float x, float y, float z, float* R) {
    float sq = x * x + y * y + z * z;
    float s = 1.0f - (sq * (1.0f / 6.0f)) * (1.0f - sq * (1.0f / 20.0f));
    float c = 0.5f - (sq * (1.0f / 24.0f)) * (1.0f - sq * (1.0f / 30.0f));
    rodrigues(x, y, z, s, c, R);
}

// Full so3_exp matching the reference branches (angles up to ~6 for xs)
__device__ __forceinline__ void so3_exp_dev(float x, float y, float z, float* R) {
    float sq = x * x + y * y + z * z;
    float angle = sqrtf(fmaxf(sq, 1e-16f));
    bool small = sq < 1e-12f;
    float a = small ? 1.0f : angle;
    float sn, cs;
    __sincosf(a, &sn, &cs);
    float s = small ? (1.0f - sq * (1.0f / 6.0f)) : (sn / a);
    float c = small ? (0.5f - sq * (1.0f / 24.0f)) : ((1.0f - cs) / (a * a));
    rodrigues(x, y, z, s, c, R);
}

// huber-sum over 3 components of log(Om^T * Xr) / HUBER
__device__ __forceinline__ float huber3_bmtm_log(const float* Om, const float* Xr) {
    float M[9];
#pragma unroll
    for (int j = 0; j < 3; ++j) {
#pragma unroll
        for (int k = 0; k < 3; ++k) {
            M[3 * j + k] = Om[0 + j] * Xr[0 + k]
                         + Om[3 + j] * Xr[3 + k]
                         + Om[6 + j] * Xr[6 + k];
        }
    }
    float tr = M[0] + M[4] + M[8];
    float cosv = 0.5f * (tr - 1.0f);
    cosv = fminf(fmaxf(cosv, -1.0f + 1e-7f), 1.0f - 1e-7f);
    float angle = acosf(cosv);
    float sn = sqrtf(fmaxf(1.0f - cosv * cosv, 0.0f));   // sin(acos(x)), angle in (0,pi)
    float sfac = angle / (2.0f * sn);
    float v0 = sfac * (M[7] - M[5]);
    float v1 = sfac * (M[2] - M[6]);
    float v2 = sfac * (M[3] - M[1]);
    float acc = 0.0f;
#pragma unroll
    for (int t = 0; t < 3; ++t) {
        float zz = (t == 0 ? v0 : (t == 1 ? v1 : v2)) * HUBER_INV;
        float az = fabsf(zz);
        acc += (az < 1.0f) ? 0.5f * zz * zz : az - 0.5f;
    }
    return acc;
}

// Ordered non-commutative butterfly combine across lanes (xor mask).
// upper==true -> partner's matrix multiplies on the left.
__device__ __forceinline__ void ordered_combine(float* A, int mask, bool upper) {
    float L[9], R[9];
#pragma unroll
    for (int t = 0; t < 9; ++t) {
        float b = __shfl_xor(A[t], mask);
        L[t] = upper ? b : A[t];
        R[t] = upper ? A[t] : b;
    }
    float C[9];
    mat_mul3(L, R, C);
#pragma unroll
    for (int t = 0; t < 9; ++t) A[t] = C[t];
}

__global__ __launch_bounds__(256, 4) void gyro_loss_kernel(const float* __restrict__ xs,
                                                           const float* __restrict__ hat_xs,
                                                           float* __restrict__ partials,
                                                           unsigned int* __restrict__ subctr,
                                                           unsigned int* __restrict__ master,
                                                           float* __restrict__ out) {
    __shared__ float lds[BLOCK * 12];   // 12 KB: 4 steps x 3 floats per thread
    __shared__ float wsum[4];
    __shared__ int is_last;
    const int tid = threadIdx.x;
    const int bid = blockIdx.x;
    const int gt = bid * BLOCK + tid;                 // global thread id

    // ---- stage this block's hat_xs slice, fully coalesced float4 ----
    const float4* gp = reinterpret_cast<const float4*>(hat_xs) + (size_t)bid * (BLOCK * 3);
    float4* lp = reinterpret_cast<float4*>(lds);
#pragma unroll
    for (int q = 0; q < 3; ++q) lp[q * BLOCK + tid] = gp[q * BLOCK + tid];
    __syncthreads();

    // ---- product of this thread's 4 per-step rotations (tree, depth 2) ----
    const float* h = &lds[12 * tid];
    float Ra[9], Rb[9], P[9], Q[9], Om[9];
    so3_exp_small(DT * h[0], DT * h[1], DT * h[2], Ra);
    so3_exp_small(DT * h[3], DT * h[4], DT * h[5], Rb);
    mat_mul3(Ra, Rb, P);
    so3_exp_small(DT * h[6], DT * h[7], DT * h[8], Ra);
    so3_exp_small(DT * h[9], DT * h[10], DT * h[11], Rb);
    mat_mul3(Ra, Rb, Q);
    mat_mul3(P, Q, Om);

    // ---- butterfly to the 16-step product (quad lanes) ----
    ordered_combine(Om, 1, (tid & 1) != 0);
    ordered_combine(Om, 2, (tid & 2) != 0);
    const int g = gt >> 2;                             // level-16 group id

    // ---- xs_r for this group (quad lanes load the same float4 -> broadcast) ----
    float4 xv = *(reinterpret_cast<const float4*>(xs) + (size_t)g * 12);
    float Xr[9];
    so3_exp_dev(xv.x, xv.y, xv.z, Xr);

    // keep level-16 copies, then combine to level 32 in place
    float Om16[9], Xr16[9];
#pragma unroll
    for (int t = 0; t < 9; ++t) { Om16[t] = Om[t]; Xr16[t] = Xr[t]; }
    ordered_combine(Om, 4, (tid & 4) != 0);
    ordered_combine(Xr, 4, (tid & 4) != 0);

    // ---- one predicated huber/log section on disjoint lanes ----
    bool do16 = ((tid & 3) == 1) && ((g & (G16_PER_SEQ - 1)) >= N0);
    bool do32 = ((tid & 7) == 0) && (((g >> 1) & (G16_PER_SEQ / 2 - 1)) >= N0);
    float partial = 0.0f;
    if (do16 || do32) {
        float A[9], B[9];
#pragma unroll
        for (int t = 0; t < 9; ++t) {
            A[t] = do32 ? Om[t] : Om16[t];
            B[t] = do32 ? Xr[t] : Xr16[t];
        }
        float w = do32 ? C32 : C16;
        partial = w * huber3_bmtm_log(A, B);
    }

    // ---- block reduction ----
    if (tid == 0) is_last = 0;
#pragma unroll
    for (int off = 32; off > 0; off >>= 1) partial += __shfl_down(partial, off);
    if ((tid & 63) == 0) wsum[tid >> 6] = partial;
    __syncthreads();                                   // covers wsum and is_last=0

    // ---- finish protocol: distributed atomics, hierarchical counters ----
    if (tid == 0) {
        float bsum = wsum[0] + wsum[1] + wsum[2] + wsum[3];
        atomicAdd(&partials[bid], bsum);               // distinct address per block
        __threadfence();
        unsigned int o = atomicAdd(&subctr[(bid & 63) * 32], 1u);  // own 128B line
        if (o == 31u) {                                // last of this sub-group
            unsigned int m = atomicAdd(master, 1u);
            if (m == 63u) is_last = 1;                 // globally last block
        }
    }
    __syncthreads();

    if (is_last) {
        __threadfence();
        float s = 0.0f;
#pragma unroll
        for (int q = 0; q < NBLOCKS / BLOCK; ++q)
            s += atomicAdd(&partials[q * BLOCK + tid], 0.0f);  // coherent read
#pragma unroll
        for (int off = 32; off > 0; off >>= 1) s += __shfl_down(s, off);
        if ((tid & 63) == 0) wsum[tid >> 6] = s;
        __syncthreads();
        if (tid == 0) out[0] = wsum[0] + wsum[1] + wsum[2] + wsum[3];
    }
}

extern "C" void kernel_launch(void* const* d_in, const int* in_sizes, int n_in,
                              void* d_out, int out_size, void* d_ws, size_t ws_size,
                              hipStream_t stream) {
    const float* xs     = (const float*)d_in[0];
    // d_in[1] = dp, unused by the forward pass
    const float* hat_xs = (const float*)d_in[2];
    float* out = (float*)d_out;

    float* partials     = (float*)d_ws;
    unsigned int* subctr = (unsigned int*)d_ws + WS_SUBCTR_U32;
    unsigned int* master = (unsigned int*)d_ws + WS_MASTER_U32;

    hipMemsetAsync(d_ws, 0, WS_ZERO_BYTES, stream);
    gyro_loss_kernel<<<NBLOCKS, BLOCK, 0, stream>>>(xs, hat_xs, partials, subctr, master, out);
}

// Round 5
// 90.421 us; speedup vs baseline: 1.5851x; 1.5175x over previous
//
#include <hip/hip_runtime.h>
#include <math.h>

// Problem constants (match reference)
#define NSEQ 64
#define TLEN 32768
#define G16_PER_SEQ 2048               // TLEN/16
#define NG16 (NSEQ * G16_PER_SEQ)      // 131072 level-16 groups
#define NTHREADS (NG16 * 4)            // 524288 threads, 4 gyro steps each
#define BLOCK 256
#define NBLOCKS (NTHREADS / BLOCK)     // 2048
#define N0 5
#define DT 0.01f
#define HUBER_INV 200.0f               // 1/0.005

// W*HUBER^2 = 25.  mean denominators: 64*2043*3 and 64*1019*3; level-32 extra 1/2.
__device__ __constant__ float C16 = 25.0f / (64.0f * 2043.0f * 3.0f);
__device__ __constant__ float C32 = 12.5f / (64.0f * 1019.0f * 3.0f);

// Quaternions q = {w, x, y, z}; R(q1)R(q2) = R(q1 o q2) (Hamilton product).
__device__ __forceinline__ void qmul(const float* a, const float* b, float* c) {
    c[0] = a[0] * b[0] - a[1] * b[1] - a[2] * b[2] - a[3] * b[3];
    c[1] = a[0] * b[1] + a[1] * b[0] + a[2] * b[3] - a[3] * b[2];
    c[2] = a[0] * b[2] + a[2] * b[0] + a[3] * b[1] - a[1] * b[3];
    c[3] = a[0] * b[3] + a[3] * b[0] + a[1] * b[2] - a[2] * b[1];
}

// exp(phi) as quat, small-angle series at half angle. |phi| <= ~0.06 here,
// so err ~1e-12: w = cos(a/2), k = sin(a/2)/a, v = k*phi.
__device__ __forceinline__ void qexp_small(float x, float y, float z, float* q) {
    float sq = x * x + y * y + z * z;                       // a^2
    float w = 1.0f - (sq * 0.125f) * (1.0f - sq * (1.0f / 48.0f));
    float k = 0.5f - (sq * (1.0f / 48.0f)) * (1.0f - sq * (1.0f / 80.0f));
    q[0] = w; q[1] = k * x; q[2] = k * y; q[3] = k * z;
}

// exp(phi) as quat, full range (xs angles up to ~6), matching reference branches.
__device__ __forceinline__ void qexp_full(float x, float y, float z, float* q) {
    float sq = x * x + y * y + z * z;
    float a = sqrtf(fmaxf(sq, 1e-16f));
    bool small = sq < 1e-12f;
    float sn, cs;
    __sincosf(0.5f * a, &sn, &cs);
    float w = small ? 1.0f - sq * 0.125f : cs;              // cos(a/2)
    float k = small ? 0.5f - sq * (1.0f / 48.0f) : sn / a;  // sin(a/2)/a
    q[0] = w; q[1] = k * x; q[2] = k * y; q[3] = k * z;
}

// huber-sum of log(R(o)^T R(x)) / HUBER via q_rel = conj(o) o x.
// cos(angle) = 2w^2-1 and vee = 4*w*v are both invariant under q -> -q,
// so this reproduces the reference's short-rotation acos branch exactly.
__device__ __forceinline__ float huber3_q(const float* o, const float* x) {
    float rw = o[0] * x[0] + o[1] * x[1] + o[2] * x[2] + o[3] * x[3];
    float rx = o[0] * x[1] - o[1] * x[0] - (o[2] * x[3] - o[3] * x[2]);
    float ry = o[0] * x[2] - o[2] * x[0] - (o[3] * x[1] - o[1] * x[3]);
    float rz = o[0] * x[3] - o[3] * x[0] - (o[1] * x[2] - o[2] * x[1]);
    float cosv = 2.0f * rw * rw - 1.0f;
    cosv = fminf(fmaxf(cosv, -1.0f + 1e-7f), 1.0f - 1e-7f);
    float angle = acosf(cosv);
    float sn = sqrtf(fmaxf(1.0f - cosv * cosv, 0.0f));      // sin(angle), in (0,pi)
    float f = (angle / (2.0f * sn)) * 4.0f * rw;            // sfac * 4w
    float v0 = f * rx, v1 = f * ry, v2 = f * rz;
    float acc = 0.0f;
#pragma unroll
    for (int t = 0; t < 3; ++t) {
        float zz = (t == 0 ? v0 : (t == 1 ? v1 : v2)) * HUBER_INV;
        float az = fabsf(zz);
        acc += (az < 1.0f) ? 0.5f * zz * zz : az - 0.5f;
    }
    return acc;
}

// Ordered non-commutative butterfly combine across lanes (xor mask).
// Lower lane holds earlier steps -> lower lane's quat multiplies on the left.
__device__ __forceinline__ void ordered_combine_q(float* q, int mask, bool upper) {
    float p[4], L[4], R[4], c[4];
#pragma unroll
    for (int t = 0; t < 4; ++t) {
        p[t] = __shfl_xor(q[t], mask);
        L[t] = upper ? p[t] : q[t];
        R[t] = upper ? q[t] : p[t];
    }
    qmul(L, R, c);
#pragma unroll
    for (int t = 0; t < 4; ++t) q[t] = c[t];
}

__global__ __launch_bounds__(256, 8) void gyro_loss_kernel(const float* __restrict__ xs,
                                                           const float* __restrict__ hat_xs,
                                                           float* __restrict__ partials) {
    __shared__ float lds[BLOCK * 12];   // 12 KB: 4 steps x 3 floats per thread
    const int tid = threadIdx.x;
    const int bid = blockIdx.x;
    const int gt = bid * BLOCK + tid;                 // global thread id

    // ---- stage this block's hat_xs slice, fully coalesced float4 ----
    const float4* gp = reinterpret_cast<const float4*>(hat_xs) + (size_t)bid * (BLOCK * 3);
    float4* lp = reinterpret_cast<float4*>(lds);
#pragma unroll
    for (int q = 0; q < 3; ++q) lp[q * BLOCK + tid] = gp[q * BLOCK + tid];
    __syncthreads();

    // ---- product of this thread's 4 per-step rotations (tree, depth 2) ----
    const float* h = &lds[12 * tid];
    float qa[4], qb[4], qp[4], qq[4], Om[4];
    qexp_small(DT * h[0], DT * h[1], DT * h[2], qa);
    qexp_small(DT * h[3], DT * h[4], DT * h[5], qb);
    qmul(qa, qb, qp);
    qexp_small(DT * h[6], DT * h[7], DT * h[8], qa);
    qexp_small(DT * h[9], DT * h[10], DT * h[11], qb);
    qmul(qa, qb, qq);
    qmul(qp, qq, Om);

    // ---- butterfly to the 16-step product (quad lanes; DPP shuffles) ----
    ordered_combine_q(Om, 1, (tid & 1) != 0);
    ordered_combine_q(Om, 2, (tid & 2) != 0);
    const int g = gt >> 2;                             // level-16 group id

    // ---- xs_r for this group (quad lanes load the same float4 -> broadcast) ----
    float4 xv = *(reinterpret_cast<const float4*>(xs) + (size_t)g * 12);
    float Xr[4];
    qexp_full(xv.x, xv.y, xv.z, Xr);

    // ---- level-16 term (R2-proven structure: section before level-32 combine) ----
    float partial = 0.0f;
    if ((tid & 3) == 0 && (g & (G16_PER_SEQ - 1)) >= N0)
        partial = C16 * huber3_q(Om, Xr);

    // ---- level 32: combine adjacent quads (xor 4) for both Om and Xr ----
    ordered_combine_q(Om, 4, (tid & 4) != 0);
    ordered_combine_q(Xr, 4, (tid & 4) != 0);
    if ((tid & 7) == 0 && ((g >> 1) & (G16_PER_SEQ / 2 - 1)) >= N0)
        partial += C32 * huber3_q(Om, Xr);

    // ---- block reduction -> plain store, no atomics/fences in the hot kernel ----
#pragma unroll
    for (int off = 32; off > 0; off >>= 1) partial += __shfl_down(partial, off);
    __shared__ float wsum[4];
    if ((tid & 63) == 0) wsum[tid >> 6] = partial;
    __syncthreads();
    if (tid == 0) partials[bid] = wsum[0] + wsum[1] + wsum[2] + wsum[3];
}

__global__ __launch_bounds__(256) void finish_kernel(const float* __restrict__ partials,
                                                     float* __restrict__ out) {
    const int tid = threadIdx.x;
    float s = 0.0f;
#pragma unroll
    for (int q = 0; q < NBLOCKS / 256; ++q) s += partials[q * 256 + tid];
#pragma unroll
    for (int off = 32; off > 0; off >>= 1) s += __shfl_down(s, off);
    __shared__ float wsum[4];
    if ((tid & 63) == 0) wsum[tid >> 6] = s;
    __syncthreads();
    if (tid == 0) out[0] = wsum[0] + wsum[1] + wsum[2] + wsum[3];
}

extern "C" void kernel_launch(void* const* d_in, const int* in_sizes, int n_in,
                              void* d_out, int out_size, void* d_ws, size_t ws_size,
                              hipStream_t stream) {
    const float* xs     = (const float*)d_in[0];
    // d_in[1] = dp, unused by the forward pass
    const float* hat_xs = (const float*)d_in[2];
    float* out = (float*)d_out;
    float* partials = (float*)d_ws;     // NBLOCKS floats, every one written before read

    gyro_loss_kernel<<<NBLOCKS, BLOCK, 0, stream>>>(xs, hat_xs, partials);
    finish_kernel<<<1, 256, 0, stream>>>(partials, out);
}